// Round 9
// baseline (120.701 us; speedup 1.0000x reference)
//
#include <hip/hip_runtime.h>
#include <hip/hip_bf16.h>
#include <math.h>

// QuantumStateEncoder — algebraic collapse version (R8: spill-free MLP).
// z_q = <psi1| C1' R2' C2' Z_q C2 R2 C1 |psi1>, psi1 = prod_j R1_j RX(a_j)|0>.
// See R3 notes: ring-2 -> Z-strings S_q; layer-2 Rot -> n.sigma; ring-1 via
// constexpr symplectic Pauli algebra; layer-1 Rot + RX -> per-qubit Bloch vecs.
// z_q = sum_t coef_t * prod_j r_{j,code(t,j)}  (288 terms, compile-time codes)
// R8 change: MLP1/MLP2 interleaved in 16-wide chunks so no h[64] array is
// live (R7 kernel spilled: VGPR_Count=40 with >100 declared floats ->
// scratch; VALUBusy 18% at 1 wave/SIMD). acc[32] persistent chains + h16[16]
// chunk => ~70 VGPR, zero scratch, 32-way ILP.

#define DEVINL __device__ __forceinline__

// ---------- compile-time Pauli algebra (P = i^ph * X^x * Z^z) ----------
struct Pau { unsigned x, z; int ph; };
constexpr int pcnt8(unsigned v){ int c=0; for(int i=0;i<8;++i) c+=(v>>i)&1; return c; }
constexpr Pau pmul(Pau a, Pau b){
  return Pau{a.x^b.x, a.z^b.z, (a.ph + b.ph + 2*pcnt8(a.z & b.x)) & 3};
}
constexpr Pau conjP(int j, int a){
  Pau X{ j<7 ? ((1u<<j)|(1u<<(j+1))) : 0x83u, 0u, 0 };
  Pau Z{ 0u, j>0 ? ((2u<<j)-1u) : 0xFEu, 0 };
  if (a==0) return X;
  if (a==2) return Z;
  Pau y = pmul(X, Z);
  return Pau{y.x, y.z, (y.ph+1)&3};
}
constexpr unsigned SQM[8] = {0x54,0xA8,0x05,0x0A,0x15,0x2A,0x55,0xAA};
constexpr int TPREF[9]   = {0,27,54,63,72,99,126,207,288};

struct TTab { unsigned char mx[288], my[288], mz[288]; signed char sg[288]; };
constexpr TTab gen_tt(){
  TTab T{};
  int t=0;
  for (int q=0;q<8;++q){
    int sup[8]={}; int m=0;
    for (int j=0;j<8;++j) if ((SQM[q]>>j)&1) sup[m++]=j;
    int nt=1; for (int i=0;i<m;++i) nt*=3;
    for (int a=0;a<nt;++a){
      Pau P{0u,0u,0}; int rem=a;
      for (int i=0;i<m;++i){ P = pmul(P, conjP(sup[i], rem%3)); rem/=3; }
      unsigned y = P.x & P.z;
      int tau = (P.ph + 3*pcnt8(y)) & 3;
      T.mx[t]=(unsigned char)(P.x & ~P.z);
      T.my[t]=(unsigned char)y;
      T.mz[t]=(unsigned char)(P.z & ~P.x);
      T.sg[t]=(signed char)(tau==0 ? 1 : -1);
      ++t;
    }
  }
  return T;
}
constexpr TTab TT = gen_tt();

// ---------- prep: per-qubit Bloch maps + 288 term coefficients ----------
struct cpx { float r, i; };
DEVINL cpx cmul(cpx a, cpx b){ return {a.r*b.r - a.i*b.i, a.r*b.i + a.i*b.r}; }
DEVINL cpx cconj(cpx a){ return {a.r, -a.i}; }
DEVINL cpx cadd(cpx a, cpx b){ return {a.r+b.r, a.i+b.i}; }

DEVINL void buildR(const float* qw3, cpx R[2][2]){
  float phi=qw3[0], th=qw3[1], om=qw3[2], s,c,sp,cp,sm,cm;
  sincosf(0.5f*th,&s,&c);
  sincosf(0.5f*(phi+om),&sp,&cp);
  sincosf(0.5f*(phi-om),&sm,&cm);
  R[0][0]={cp*c,-sp*c}; R[0][1]={-cm*s,-sm*s};
  R[1][0]={cm*s,-sm*s}; R[1][1]={cp*c, sp*c};
}
DEVINL void conjH(const cpx R[2][2], const cpx S[2][2], cpx H[2][2]){
  cpx M[2][2];
  for (int i=0;i<2;++i) for (int j=0;j<2;++j)
    M[i][j] = cadd(cmul(S[i][0],R[0][j]), cmul(S[i][1],R[1][j]));
  for (int i=0;i<2;++i) for (int j=0;j<2;++j)
    H[i][j] = cadd(cmul(cconj(R[0][i]),M[0][j]), cmul(cconj(R[1][i]),M[1][j]));
}

// ws layout: [0..47] per-qubit {AYx,AYy,AYz,AZx,AZy,AZz}; [48..335] coefs
__global__ void prep_kernel(const float* __restrict__ qw, float* __restrict__ ws){
  __shared__ float n_sh[8][3];
  const int tid = threadIdx.x;
  if (tid < 8){
    const int q = tid;
    cpx R1[2][2], R2[2][2], H[2][2];
    buildR(qw + q*3,      R1);
    buildR(qw + 24 + q*3, R2);
    const cpx SX[2][2] = {{{0,0},{1,0}},{{1,0},{0,0}}};
    const cpx SY[2][2] = {{{0,0},{0,-1}},{{0,1},{0,0}}};
    const cpx SZ[2][2] = {{{1,0},{0,0}},{{0,0},{-1,0}}};
    conjH(R1,SX,H); ws[q*6+0] = -H[0][1].i; ws[q*6+3] = H[0][0].r;
    conjH(R1,SY,H); ws[q*6+1] = -H[0][1].i; ws[q*6+4] = H[0][0].r;
    conjH(R1,SZ,H); ws[q*6+2] = -H[0][1].i; ws[q*6+5] = H[0][0].r;
    conjH(R2,SZ,H);
    n_sh[q][0] = H[0][1].r;
    n_sh[q][1] = -H[0][1].i;
    n_sh[q][2] = H[0][0].r;
  }
  __syncthreads();
  if (tid < 288){
    int q = 0;
    while (tid >= TPREF[q+1]) ++q;
    int rem = tid - TPREF[q];
    float coef = (float)TT.sg[tid];
    unsigned m = SQM[q];
    while (m){
      int j = __ffs(m) - 1; m &= m - 1;
      coef *= n_sh[j][rem % 3];
      rem /= 3;
    }
    ws[48 + tid] = coef;
  }
}

// ---------- main: one sample per lane, spill-free fused MLP ----------
DEVINL float tanh_fast(float v){
  float e = __expf(2.f*v);
  return 1.f - 2.f/(e + 1.f);
}

__global__ __launch_bounds__(256)
void qnet_pauli(const float* __restrict__ x, const float* __restrict__ Wp,
                const float* __restrict__ bp, const float* __restrict__ ws,
                const float* __restrict__ W1, const float* __restrict__ b1,
                const float* __restrict__ W2, const float* __restrict__ b2,
                float* __restrict__ out, int B){
  __shared__ float sh_x[256*17];
  const int tid = threadIdx.x;
  const int b   = blockIdx.x*256 + tid;
  const int base = blockIdx.x*256*17;
  const int lim  = B*17 - base;
#pragma unroll
  for (int i = 0; i < 17; ++i){
    int o = i*256 + tid;
    if (o < lim) sh_x[o] = x[base + o];
  }
  __syncthreads();
  if (b >= B) return;

  // ---- angles + Bloch vectors per qubit (xv dead after this block) ----
  float rx[8], ry[8], rz[8];
  {
    float xv[17];
#pragma unroll
    for (int k=0;k<17;++k) xv[k] = sh_x[tid*17 + k];
#pragma unroll
    for (int q=0;q<8;++q){
      float ang = bp[q];
#pragma unroll
      for (int k=0;k<17;++k) ang = fmaf(xv[k], Wp[q*17+k], ang);
      float sa, ca;
      __sincosf(ang, &sa, &ca);
      rx[q] = ca*ws[q*6+3] - sa*ws[q*6+0];
      ry[q] = ca*ws[q*6+4] - sa*ws[q*6+1];
      rz[q] = ca*ws[q*6+5] - sa*ws[q*6+2];
    }
  }

  // ---- z_q = sum_t coef_t * prod_j r_{j,code} ----
  const float* cf = ws + 48;
  float zz[8];
#pragma unroll
  for (int q=0;q<8;++q){
    float acc = 0.f;
#pragma unroll
    for (int t=TPREF[q]; t<TPREF[q+1]; ++t){
      float p = cf[t];
#pragma unroll
      for (int j=0;j<8;++j){
        if (TT.mx[t] & (1u<<j)) p *= rx[j];
        if (TT.my[t] & (1u<<j)) p *= ry[j];
        if (TT.mz[t] & (1u<<j)) p *= rz[j];
      }
      acc += p;
    }
    zz[q] = acc;
  }
  // rx/ry/rz dead here.

  // ---- fused MLP, 16-wide h chunks, 32 persistent acc chains ----
  float acc[32];
#pragma unroll
  for (int j=0;j<32;++j) acc[j] = b2[j];

#pragma unroll
  for (int lc=0; lc<4; ++lc){
    float h16[16];
#pragma unroll
    for (int i=0;i<16;++i){
      const int l = lc*16 + i;
      float hl = b1[l];
#pragma unroll
      for (int q=0;q<8;++q) hl = fmaf(zz[q], W1[l*8+q], hl);
      h16[i] = fmaxf(hl, 0.f);
    }
#pragma unroll
    for (int j=0;j<32;++j){
      const float4* w2p = (const float4*)(W2 + j*64 + lc*16);
      float4 wa = w2p[0], wb = w2p[1], wc = w2p[2], wd = w2p[3];
      float a = acc[j];
      a = fmaf(h16[ 0], wa.x, a); a = fmaf(h16[ 1], wa.y, a);
      a = fmaf(h16[ 2], wa.z, a); a = fmaf(h16[ 3], wa.w, a);
      a = fmaf(h16[ 4], wb.x, a); a = fmaf(h16[ 5], wb.y, a);
      a = fmaf(h16[ 6], wb.z, a); a = fmaf(h16[ 7], wb.w, a);
      a = fmaf(h16[ 8], wc.x, a); a = fmaf(h16[ 9], wc.y, a);
      a = fmaf(h16[10], wc.z, a); a = fmaf(h16[11], wc.w, a);
      a = fmaf(h16[12], wd.x, a); a = fmaf(h16[13], wd.y, a);
      a = fmaf(h16[14], wd.z, a); a = fmaf(h16[15], wd.w, a);
      acc[j] = a;
    }
  }

  // ---- tanh + vectorized store ----
  float4* op4 = (float4*)(out + (size_t)b*32);
#pragma unroll
  for (int jj=0;jj<8;++jj){
    float4 v;
    v.x = tanh_fast(acc[jj*4+0]);
    v.y = tanh_fast(acc[jj*4+1]);
    v.z = tanh_fast(acc[jj*4+2]);
    v.w = tanh_fast(acc[jj*4+3]);
    op4[jj] = v;
  }
}

extern "C" void kernel_launch(void* const* d_in, const int* in_sizes, int n_in,
                              void* d_out, int out_size, void* d_ws, size_t ws_size,
                              hipStream_t stream) {
  const float* x  = (const float*)d_in[0];
  const float* Wp = (const float*)d_in[1];
  const float* bp = (const float*)d_in[2];
  const float* qw = (const float*)d_in[3];
  const float* W1 = (const float*)d_in[4];
  const float* b1 = (const float*)d_in[5];
  const float* W2 = (const float*)d_in[6];
  const float* b2 = (const float*)d_in[7];
  float* out = (float*)d_out;
  const int B = in_sizes[0] / 17;   // 65536

  prep_kernel<<<1, 288, 0, stream>>>(qw, (float*)d_ws);
  qnet_pauli<<<(B + 255)/256, 256, 0, stream>>>(x, Wp, bp, (const float*)d_ws,
                                                W1, b1, W2, b2, out, B);
}

// Round 10
// 101.001 us; speedup vs baseline: 1.1950x; 1.1950x over previous
//
#include <hip/hip_runtime.h>
#include <hip/hip_bf16.h>
#include <math.h>

// QuantumStateEncoder — algebraic collapse (R9: LDS-staged weights).
// R8 post-mortem: 1 wave/SIMD (1024 waves total), per-lane uniform weight
// loads from global (L2 ~200cyc) fully exposed -> VALUBusy 15%. R9: stage
// all weights (ws 336 + Wp 136 + bp 8 + W1 512 + b1 64 + W2 2048 + b2 32
// = 3136 floats) into LDS once per block; inner loops read LDS only.

#define DEVINL __device__ __forceinline__

// ---------- compile-time Pauli algebra (P = i^ph * X^x * Z^z) ----------
struct Pau { unsigned x, z; int ph; };
constexpr int pcnt8(unsigned v){ int c=0; for(int i=0;i<8;++i) c+=(v>>i)&1; return c; }
constexpr Pau pmul(Pau a, Pau b){
  return Pau{a.x^b.x, a.z^b.z, (a.ph + b.ph + 2*pcnt8(a.z & b.x)) & 3};
}
constexpr Pau conjP(int j, int a){
  Pau X{ j<7 ? ((1u<<j)|(1u<<(j+1))) : 0x83u, 0u, 0 };
  Pau Z{ 0u, j>0 ? ((2u<<j)-1u) : 0xFEu, 0 };
  if (a==0) return X;
  if (a==2) return Z;
  Pau y = pmul(X, Z);
  return Pau{y.x, y.z, (y.ph+1)&3};
}
constexpr unsigned SQM[8] = {0x54,0xA8,0x05,0x0A,0x15,0x2A,0x55,0xAA};
constexpr int TPREF[9]   = {0,27,54,63,72,99,126,207,288};

struct TTab { unsigned char mx[288], my[288], mz[288]; signed char sg[288]; };
constexpr TTab gen_tt(){
  TTab T{};
  int t=0;
  for (int q=0;q<8;++q){
    int sup[8]={}; int m=0;
    for (int j=0;j<8;++j) if ((SQM[q]>>j)&1) sup[m++]=j;
    int nt=1; for (int i=0;i<m;++i) nt*=3;
    for (int a=0;a<nt;++a){
      Pau P{0u,0u,0}; int rem=a;
      for (int i=0;i<m;++i){ P = pmul(P, conjP(sup[i], rem%3)); rem/=3; }
      unsigned y = P.x & P.z;
      int tau = (P.ph + 3*pcnt8(y)) & 3;
      T.mx[t]=(unsigned char)(P.x & ~P.z);
      T.my[t]=(unsigned char)y;
      T.mz[t]=(unsigned char)(P.z & ~P.x);
      T.sg[t]=(signed char)(tau==0 ? 1 : -1);
      ++t;
    }
  }
  return T;
}
constexpr TTab TT = gen_tt();

// ---------- prep: per-qubit Bloch maps + 288 term coefficients ----------
struct cpx { float r, i; };
DEVINL cpx cmul(cpx a, cpx b){ return {a.r*b.r - a.i*b.i, a.r*b.i + a.i*b.r}; }
DEVINL cpx cconj(cpx a){ return {a.r, -a.i}; }
DEVINL cpx cadd(cpx a, cpx b){ return {a.r+b.r, a.i+b.i}; }

DEVINL void buildR(const float* qw3, cpx R[2][2]){
  float phi=qw3[0], th=qw3[1], om=qw3[2], s,c,sp,cp,sm,cm;
  sincosf(0.5f*th,&s,&c);
  sincosf(0.5f*(phi+om),&sp,&cp);
  sincosf(0.5f*(phi-om),&sm,&cm);
  R[0][0]={cp*c,-sp*c}; R[0][1]={-cm*s,-sm*s};
  R[1][0]={cm*s,-sm*s}; R[1][1]={cp*c, sp*c};
}
DEVINL void conjH(const cpx R[2][2], const cpx S[2][2], cpx H[2][2]){
  cpx M[2][2];
  for (int i=0;i<2;++i) for (int j=0;j<2;++j)
    M[i][j] = cadd(cmul(S[i][0],R[0][j]), cmul(S[i][1],R[1][j]));
  for (int i=0;i<2;++i) for (int j=0;j<2;++j)
    H[i][j] = cadd(cmul(cconj(R[0][i]),M[0][j]), cmul(cconj(R[1][i]),M[1][j]));
}

// ws layout: [0..47] per-qubit {AYx,AYy,AYz,AZx,AZy,AZz}; [48..335] coefs
__global__ void prep_kernel(const float* __restrict__ qw, float* __restrict__ ws){
  __shared__ float n_sh[8][3];
  const int tid = threadIdx.x;
  if (tid < 8){
    const int q = tid;
    cpx R1[2][2], R2[2][2], H[2][2];
    buildR(qw + q*3,      R1);
    buildR(qw + 24 + q*3, R2);
    const cpx SX[2][2] = {{{0,0},{1,0}},{{1,0},{0,0}}};
    const cpx SY[2][2] = {{{0,0},{0,-1}},{{0,1},{0,0}}};
    const cpx SZ[2][2] = {{{1,0},{0,0}},{{0,0},{-1,0}}};
    conjH(R1,SX,H); ws[q*6+0] = -H[0][1].i; ws[q*6+3] = H[0][0].r;
    conjH(R1,SY,H); ws[q*6+1] = -H[0][1].i; ws[q*6+4] = H[0][0].r;
    conjH(R1,SZ,H); ws[q*6+2] = -H[0][1].i; ws[q*6+5] = H[0][0].r;
    conjH(R2,SZ,H);
    n_sh[q][0] = H[0][1].r;
    n_sh[q][1] = -H[0][1].i;
    n_sh[q][2] = H[0][0].r;
  }
  __syncthreads();
  if (tid < 288){
    int q = 0;
    while (tid >= TPREF[q+1]) ++q;
    int rem = tid - TPREF[q];
    float coef = (float)TT.sg[tid];
    unsigned m = SQM[q];
    while (m){
      int j = __ffs(m) - 1; m &= m - 1;
      coef *= n_sh[j][rem % 3];
      rem /= 3;
    }
    ws[48 + tid] = coef;
  }
}

// ---------- main: one sample per lane, all weights in LDS ----------
DEVINL float tanh_fast(float v){
  float e = __expf(2.f*v);
  return 1.f - 2.f/(e + 1.f);
}

__global__ __launch_bounds__(256)
void qnet_pauli(const float* __restrict__ x, const float* __restrict__ Wp,
                const float* __restrict__ bp, const float* __restrict__ ws,
                const float* __restrict__ W1, const float* __restrict__ b1,
                const float* __restrict__ W2, const float* __restrict__ b2,
                float* __restrict__ out, int B){
  // LDS: weights 3136 floats + x tile 4352 floats = 29952 B
  __shared__ __align__(16) float smem[3136 + 256*17];
  float* sws = smem;          // 336: A maps(48) + coefs(288)
  float* sWp = smem + 336;    // 136
  float* sbp = smem + 472;    // 8
  float* sW1 = smem + 480;    // 512 (16B-aligned: 480*4)
  float* sb1 = smem + 992;    // 64
  float* sW2 = smem + 1056;   // 2048 (16B-aligned)
  float* sb2 = smem + 3104;   // 32
  float* shx = smem + 3136;   // 4352 (16B-aligned)

  const int tid = threadIdx.x;
  const int b   = blockIdx.x*256 + tid;

  // ---- stage weights (coalesced, once per block) ----
  for (int i = tid; i < 336;  i += 256) sws[i] = ws[i];
  for (int i = tid; i < 136;  i += 256) sWp[i] = Wp[i];
  if (tid < 8)  sbp[tid] = bp[tid];
  for (int i = tid; i < 512;  i += 256) sW1[i] = W1[i];
  if (tid < 64) sb1[tid] = b1[tid];
  for (int i = tid; i < 2048; i += 256) sW2[i] = W2[i];
  if (tid < 32) sb2[tid] = b2[tid];

  // ---- stage this block's x rows (coalesced) ----
  const int base = blockIdx.x*256*17;
  const int lim  = B*17 - base;
#pragma unroll
  for (int i = 0; i < 17; ++i){
    int o = i*256 + tid;
    if (o < lim) shx[o] = x[base + o];
  }
  __syncthreads();
  if (b >= B) return;

  // ---- angles + Bloch vectors per qubit ----
  float rx[8], ry[8], rz[8];
  {
    float xv[17];
#pragma unroll
    for (int k=0;k<17;++k) xv[k] = shx[tid*17 + k];
#pragma unroll
    for (int q=0;q<8;++q){
      float ang = sbp[q];
#pragma unroll
      for (int k=0;k<17;++k) ang = fmaf(xv[k], sWp[q*17+k], ang);
      float sa, ca;
      __sincosf(ang, &sa, &ca);
      rx[q] = ca*sws[q*6+3] - sa*sws[q*6+0];
      ry[q] = ca*sws[q*6+4] - sa*sws[q*6+1];
      rz[q] = ca*sws[q*6+5] - sa*sws[q*6+2];
    }
  }

  // ---- z_q = sum_t coef_t * prod_j r_{j,code} ----
  const float* cf = sws + 48;
  float zz[8];
#pragma unroll
  for (int q=0;q<8;++q){
    float acc = 0.f;
#pragma unroll
    for (int t=TPREF[q]; t<TPREF[q+1]; ++t){
      float p = cf[t];
#pragma unroll
      for (int j=0;j<8;++j){
        if (TT.mx[t] & (1u<<j)) p *= rx[j];
        if (TT.my[t] & (1u<<j)) p *= ry[j];
        if (TT.mz[t] & (1u<<j)) p *= rz[j];
      }
      acc += p;
    }
    zz[q] = acc;
  }

  // ---- fused MLP, 16-wide h chunks, 32 persistent acc chains ----
  float acc[32];
#pragma unroll
  for (int j=0;j<32;++j) acc[j] = sb2[j];

#pragma unroll
  for (int lc=0; lc<4; ++lc){
    float h16[16];
#pragma unroll
    for (int i=0;i<16;++i){
      const int l = lc*16 + i;
      const float4* w1p = (const float4*)(sW1 + l*8);
      float4 wA = w1p[0], wB = w1p[1];
      float hl = sb1[l];
      hl = fmaf(zz[0], wA.x, hl); hl = fmaf(zz[1], wA.y, hl);
      hl = fmaf(zz[2], wA.z, hl); hl = fmaf(zz[3], wA.w, hl);
      hl = fmaf(zz[4], wB.x, hl); hl = fmaf(zz[5], wB.y, hl);
      hl = fmaf(zz[6], wB.z, hl); hl = fmaf(zz[7], wB.w, hl);
      h16[i] = fmaxf(hl, 0.f);
    }
#pragma unroll
    for (int j=0;j<32;++j){
      const float4* w2p = (const float4*)(sW2 + j*64 + lc*16);
      float4 wa = w2p[0], wb = w2p[1], wc = w2p[2], wd = w2p[3];
      float a = acc[j];
      a = fmaf(h16[ 0], wa.x, a); a = fmaf(h16[ 1], wa.y, a);
      a = fmaf(h16[ 2], wa.z, a); a = fmaf(h16[ 3], wa.w, a);
      a = fmaf(h16[ 4], wb.x, a); a = fmaf(h16[ 5], wb.y, a);
      a = fmaf(h16[ 6], wb.z, a); a = fmaf(h16[ 7], wb.w, a);
      a = fmaf(h16[ 8], wc.x, a); a = fmaf(h16[ 9], wc.y, a);
      a = fmaf(h16[10], wc.z, a); a = fmaf(h16[11], wc.w, a);
      a = fmaf(h16[12], wd.x, a); a = fmaf(h16[13], wd.y, a);
      a = fmaf(h16[14], wd.z, a); a = fmaf(h16[15], wd.w, a);
      acc[j] = a;
    }
  }

  // ---- tanh + vectorized store ----
  float4* op4 = (float4*)(out + (size_t)b*32);
#pragma unroll
  for (int jj=0;jj<8;++jj){
    float4 v;
    v.x = tanh_fast(acc[jj*4+0]);
    v.y = tanh_fast(acc[jj*4+1]);
    v.z = tanh_fast(acc[jj*4+2]);
    v.w = tanh_fast(acc[jj*4+3]);
    op4[jj] = v;
  }
}

extern "C" void kernel_launch(void* const* d_in, const int* in_sizes, int n_in,
                              void* d_out, int out_size, void* d_ws, size_t ws_size,
                              hipStream_t stream) {
  const float* x  = (const float*)d_in[0];
  const float* Wp = (const float*)d_in[1];
  const float* bp = (const float*)d_in[2];
  const float* qw = (const float*)d_in[3];
  const float* W1 = (const float*)d_in[4];
  const float* b1 = (const float*)d_in[5];
  const float* W2 = (const float*)d_in[6];
  const float* b2 = (const float*)d_in[7];
  float* out = (float*)d_out;
  const int B = in_sizes[0] / 17;   // 65536

  prep_kernel<<<1, 288, 0, stream>>>(qw, (float*)d_ws);
  qnet_pauli<<<(B + 255)/256, 256, 0, stream>>>(x, Wp, bp, (const float*)d_ws,
                                                W1, b1, W2, b2, out, B);
}

// Round 13
// 89.412 us; speedup vs baseline: 1.3500x; 1.1296x over previous
//
#include <hip/hip_runtime.h>
#include <hip/hip_bf16.h>
#include <math.h>

// QuantumStateEncoder — algebraic collapse (R10: 4 lanes/sample TLP).
// R9 post-mortem: 1 sample/lane = 1024 waves = 1 wave/SIMD -> zero TLP;
// LDS-staged weights cut latency/stall (53->~33us) but dependent ds_read->fma
// chains still expose ~100cyc bubbles nothing fills. R10: block=256 handles
// 64 samples; the 4 waves take wave-uniform ROLES per phase (terms need
// compile-time tables -> role must be per-wave, not per-lane, else 4-way
// divergence serializes). 4096 waves total = 4 waves/SIMD.
// Phases: A angles+Bloch (wave w: qubits 2w,2w+1) | B terms quarter
// [72w,72w+72) -> partial zz | C1 h[16w..+16) | C2 out[8w..+8) | store.
// LDS overlaid by lifetime: 38.1 KB -> 4 blocks/CU.

#define DEVINL __device__ __forceinline__

// ---------- compile-time Pauli algebra (P = i^ph * X^x * Z^z) ----------
struct Pau { unsigned x, z; int ph; };
constexpr int pcnt8(unsigned v){ int c=0; for(int i=0;i<8;++i) c+=(v>>i)&1; return c; }
constexpr Pau pmul(Pau a, Pau b){
  return Pau{a.x^b.x, a.z^b.z, (a.ph + b.ph + 2*pcnt8(a.z & b.x)) & 3};
}
constexpr Pau conjP(int j, int a){
  Pau X{ j<7 ? ((1u<<j)|(1u<<(j+1))) : 0x83u, 0u, 0 };
  Pau Z{ 0u, j>0 ? ((2u<<j)-1u) : 0xFEu, 0 };
  if (a==0) return X;
  if (a==2) return Z;
  Pau y = pmul(X, Z);
  return Pau{y.x, y.z, (y.ph+1)&3};
}
constexpr unsigned SQM[8] = {0x54,0xA8,0x05,0x0A,0x15,0x2A,0x55,0xAA};
constexpr int TPREF[9]   = {0,27,54,63,72,99,126,207,288};

struct TTab { unsigned char mx[288], my[288], mz[288]; signed char sg[288]; };
constexpr TTab gen_tt(){
  TTab T{};
  int t=0;
  for (int q=0;q<8;++q){
    int sup[8]={}; int m=0;
    for (int j=0;j<8;++j) if ((SQM[q]>>j)&1) sup[m++]=j;
    int nt=1; for (int i=0;i<m;++i) nt*=3;
    for (int a=0;a<nt;++a){
      Pau P{0u,0u,0}; int rem=a;
      for (int i=0;i<m;++i){ P = pmul(P, conjP(sup[i], rem%3)); rem/=3; }
      unsigned y = P.x & P.z;
      int tau = (P.ph + 3*pcnt8(y)) & 3;
      T.mx[t]=(unsigned char)(P.x & ~P.z);
      T.my[t]=(unsigned char)y;
      T.mz[t]=(unsigned char)(P.z & ~P.x);
      T.sg[t]=(signed char)(tau==0 ? 1 : -1);
      ++t;
    }
  }
  return T;
}
constexpr TTab TT = gen_tt();

// q of term t (compile-time foldable under unroll)
constexpr int qof(int t){
  return (t<27)?0:(t<54)?1:(t<63)?2:(t<72)?3:(t<99)?4:(t<126)?5:(t<207)?6:7;
}

template<int T0, int T1>
DEVINL void terms_range(const float* __restrict__ cf, const float rx[8],
                        const float ry[8], const float rz[8], float zp[8]){
#pragma unroll
  for (int t=T0; t<T1; ++t){
    float p = cf[t];
#pragma unroll
    for (int j=0;j<8;++j){
      if (TT.mx[t] & (1u<<j)) p *= rx[j];
      if (TT.my[t] & (1u<<j)) p *= ry[j];
      if (TT.mz[t] & (1u<<j)) p *= rz[j];
    }
    zp[qof(t)] += p;
  }
}

// ---------- prep: per-qubit Bloch maps + 288 term coefficients ----------
struct cpx { float r, i; };
DEVINL cpx cmul(cpx a, cpx b){ return {a.r*b.r - a.i*b.i, a.r*b.i + a.i*b.r}; }
DEVINL cpx cconj(cpx a){ return {a.r, -a.i}; }
DEVINL cpx cadd(cpx a, cpx b){ return {a.r+b.r, a.i+b.i}; }

DEVINL void buildR(const float* qw3, cpx R[2][2]){
  float phi=qw3[0], th=qw3[1], om=qw3[2], s,c,sp,cp,sm,cm;
  sincosf(0.5f*th,&s,&c);
  sincosf(0.5f*(phi+om),&sp,&cp);
  sincosf(0.5f*(phi-om),&sm,&cm);
  R[0][0]={cp*c,-sp*c}; R[0][1]={-cm*s,-sm*s};
  R[1][0]={cm*s,-sm*s}; R[1][1]={cp*c, sp*c};
}
DEVINL void conjH(const cpx R[2][2], const cpx S[2][2], cpx H[2][2]){
  cpx M[2][2];
  for (int i=0;i<2;++i) for (int j=0;j<2;++j)
    M[i][j] = cadd(cmul(S[i][0],R[0][j]), cmul(S[i][1],R[1][j]));
  for (int i=0;i<2;++i) for (int j=0;j<2;++j)
    H[i][j] = cadd(cmul(cconj(R[0][i]),M[0][j]), cmul(cconj(R[1][i]),M[1][j]));
}

// ws layout: [0..47] per-qubit {AYx,AYy,AYz,AZx,AZy,AZz}; [48..335] coefs
__global__ void prep_kernel(const float* __restrict__ qw, float* __restrict__ ws){
  __shared__ float n_sh[8][3];
  const int tid = threadIdx.x;
  if (tid < 8){
    const int q = tid;
    cpx R1[2][2], R2[2][2], H[2][2];
    buildR(qw + q*3,      R1);
    buildR(qw + 24 + q*3, R2);
    const cpx SX[2][2] = {{{0,0},{1,0}},{{1,0},{0,0}}};
    const cpx SY[2][2] = {{{0,0},{0,-1}},{{0,1},{0,0}}};
    const cpx SZ[2][2] = {{{1,0},{0,0}},{{0,0},{-1,0}}};
    conjH(R1,SX,H); ws[q*6+0] = -H[0][1].i; ws[q*6+3] = H[0][0].r;
    conjH(R1,SY,H); ws[q*6+1] = -H[0][1].i; ws[q*6+4] = H[0][0].r;
    conjH(R1,SZ,H); ws[q*6+2] = -H[0][1].i; ws[q*6+5] = H[0][0].r;
    conjH(R2,SZ,H);
    n_sh[q][0] = H[0][1].r;
    n_sh[q][1] = -H[0][1].i;
    n_sh[q][2] = H[0][0].r;
  }
  __syncthreads();
  if (tid < 288){
    int q = 0;
    while (tid >= TPREF[q+1]) ++q;
    int rem = tid - TPREF[q];
    float coef = (float)TT.sg[tid];
    unsigned m = SQM[q];
    while (m){
      int j = __ffs(m) - 1; m &= m - 1;
      coef *= n_sh[j][rem % 3];
      rem /= 3;
    }
    ws[48 + tid] = coef;
  }
}

DEVINL float tanh_fast(float v){
  float e = __expf(2.f*v);
  return 1.f - 2.f/(e + 1.f);
}

// ---------- main: 64 samples/block, wave-uniform roles ----------
__global__ __launch_bounds__(256)
void qnet_pauli(const float* __restrict__ x, const float* __restrict__ Wp,
                const float* __restrict__ bp, const float* __restrict__ ws,
                const float* __restrict__ W1, const float* __restrict__ b1,
                const float* __restrict__ W2, const float* __restrict__ b2,
                float* __restrict__ out, int B){
  // 3136 weights + 6400 overlaid scratch = 9536 floats = 38144 B
  __shared__ __align__(16) float smem[9536];
  float* sA  = smem;          // 336: maps(48)+cf(288)  [A,B]
  float* sWp = smem + 336;    // 136                    [A]
  float* sbp = smem + 472;    // 8                      [A]
  float* sW1 = smem + 480;    // 512 (16B aligned)      [C1]
  float* sb1 = smem + 992;    // 64                     [C1]
  float* sW2 = smem + 1056;   // 2048 (16B aligned)     [C2]
  float* sb2 = smem + 3104;   // 32                     [C2]
  float* X   = smem + 3136;   // 6400 overlaid scratch
  float* pzz = X;             // [4][64][9] = 2304      [B -> C1]
  float* sbl = X + 2304;      // [3][8][64] = 1536      [A -> B]
  float* sx  = X + 3840;      // 64*17 = 1088           [stage -> A]
  float* sh  = X + 2304;      // [64][64] = 4096        [C1 -> C2] (over sbl+sx)
  float* sout= X;             // [64][33] = 2112        [C2 -> store] (over pzz)

  const int tid = threadIdx.x;
  const int l   = tid & 63;   // sample within block
  const int w   = tid >> 6;   // wave role

  // ---- stage weights + x tile (coalesced) ----
  for (int i = tid; i < 336;  i += 256) sA[i]  = ws[i];
  for (int i = tid; i < 136;  i += 256) sWp[i] = Wp[i];
  if (tid < 8)  sbp[tid] = bp[tid];
  for (int i = tid; i < 512;  i += 256) sW1[i] = W1[i];
  if (tid < 64) sb1[tid] = b1[tid];
  for (int i = tid; i < 2048; i += 256) sW2[i] = W2[i];
  if (tid < 32) sb2[tid] = b2[tid];
  const int xbase = blockIdx.x * (64*17);
  const int xlim  = B*17 - xbase;
  for (int i = tid; i < 64*17; i += 256)
    if (i < xlim) sx[i] = x[xbase + i];
  __syncthreads();

  // ---- Phase A: wave w computes qubits 2w,2w+1 for sample l ----
  {
    float xv[17];
#pragma unroll
    for (int k=0;k<17;++k) xv[k] = sx[l*17+k];
#pragma unroll
    for (int e=0;e<2;++e){
      const int q = 2*w + e;                 // wave-uniform
      float ang = sbp[q];
      const float* wp = sWp + q*17;
#pragma unroll
      for (int k=0;k<17;++k) ang = fmaf(xv[k], wp[k], ang);
      float sa, ca;
      __sincosf(ang, &sa, &ca);
      const float* Aq = sA + q*6;
      sbl[       q*64 + l] = ca*Aq[3] - sa*Aq[0];   // rx
      sbl[ 512 + q*64 + l] = ca*Aq[4] - sa*Aq[1];   // ry
      sbl[1024 + q*64 + l] = ca*Aq[5] - sa*Aq[2];   // rz
    }
  }
  __syncthreads();

  // ---- Phase B: wave w computes term quarter, partial zz ----
  {
    float rx[8], ry[8], rz[8];
#pragma unroll
    for (int q=0;q<8;++q){
      rx[q] = sbl[       q*64 + l];
      ry[q] = sbl[ 512 + q*64 + l];
      rz[q] = sbl[1024 + q*64 + l];
    }
    float zp[8] = {0,0,0,0,0,0,0,0};
    const float* cf = sA + 48;
    if      (w==0) terms_range<  0, 72>(cf, rx,ry,rz, zp);
    else if (w==1) terms_range< 72,144>(cf, rx,ry,rz, zp);
    else if (w==2) terms_range<144,216>(cf, rx,ry,rz, zp);
    else           terms_range<216,288>(cf, rx,ry,rz, zp);
    float* pz = pzz + w*576 + l*9;
#pragma unroll
    for (int q=0;q<8;++q) pz[q] = zp[q];
  }
  __syncthreads();

  // ---- Phase C1: wave w computes h[16w..16w+16) for sample l ----
  {
    float zzv[8];
#pragma unroll
    for (int q=0;q<8;++q)
      zzv[q] = pzz[l*9+q] + pzz[576 + l*9+q] + pzz[1152 + l*9+q] + pzz[1728 + l*9+q];
#pragma unroll
    for (int i=0;i<16;++i){
      const int hq = 16*w + i;               // wave-uniform
      const float4* w1p = (const float4*)(sW1 + hq*8);
      float4 wA = w1p[0], wB = w1p[1];
      float hl = sb1[hq];
      hl = fmaf(zzv[0], wA.x, hl); hl = fmaf(zzv[1], wA.y, hl);
      hl = fmaf(zzv[2], wA.z, hl); hl = fmaf(zzv[3], wA.w, hl);
      hl = fmaf(zzv[4], wB.x, hl); hl = fmaf(zzv[5], wB.y, hl);
      hl = fmaf(zzv[6], wB.z, hl); hl = fmaf(zzv[7], wB.w, hl);
      sh[hq*64 + l] = fmaxf(hl, 0.f);
    }
  }
  __syncthreads();

  // ---- Phase C2: wave w computes outputs [8w..8w+8) for sample l ----
  {
    const int j0 = 8*w;                      // wave-uniform
    float acc[8];
#pragma unroll
    for (int jj=0;jj<8;++jj) acc[jj] = sb2[j0+jj];
#pragma unroll
    for (int kc=0;kc<16;++kc){
      float hk0 = sh[(4*kc+0)*64 + l];
      float hk1 = sh[(4*kc+1)*64 + l];
      float hk2 = sh[(4*kc+2)*64 + l];
      float hk3 = sh[(4*kc+3)*64 + l];
#pragma unroll
      for (int jj=0;jj<8;++jj){
        const float4 wv = *(const float4*)(sW2 + (j0+jj)*64 + 4*kc);
        float a = acc[jj];
        a = fmaf(hk0, wv.x, a); a = fmaf(hk1, wv.y, a);
        a = fmaf(hk2, wv.z, a); a = fmaf(hk3, wv.w, a);
        acc[jj] = a;
      }
    }
#pragma unroll
    for (int jj=0;jj<8;++jj)
      sout[l*33 + j0 + jj] = tanh_fast(acc[jj]);
  }
  __syncthreads();

  // ---- coalesced store via LDS ----
  const int obase = blockIdx.x * 2048;
  const int olim  = B*32 - obase;
  for (int i = tid; i < 2048; i += 256)
    if (i < olim) out[obase + i] = sout[(i>>5)*33 + (i&31)];
}

extern "C" void kernel_launch(void* const* d_in, const int* in_sizes, int n_in,
                              void* d_out, int out_size, void* d_ws, size_t ws_size,
                              hipStream_t stream) {
  const float* x  = (const float*)d_in[0];
  const float* Wp = (const float*)d_in[1];
  const float* bp = (const float*)d_in[2];
  const float* qw = (const float*)d_in[3];
  const float* W1 = (const float*)d_in[4];
  const float* b1 = (const float*)d_in[5];
  const float* W2 = (const float*)d_in[6];
  const float* b2 = (const float*)d_in[7];
  float* out = (float*)d_out;
  const int B = in_sizes[0] / 17;   // 65536

  prep_kernel<<<1, 288, 0, stream>>>(qw, (float*)d_ws);
  qnet_pauli<<<(B + 63)/64, 256, 0, stream>>>(x, Wp, bp, (const float*)d_ws,
                                              W1, b1, W2, b2, out, B);
}